// Round 12
// baseline (202.026 us; speedup 1.0000x reference)
//
#include <hip/hip_runtime.h>
#include <hip/hip_fp16.h>
#include <cstring>

// Problem constants (fixed by reference setup_inputs)
constexpr int N_NODES = 50000;
constexpr int N_EDGES = 800000;
constexpr int DIM     = 128;
constexpr int DIM4    = DIM / 4;          // 32 float4 columns
constexpr float BN_EPS = 1e-5f;

constexpr int EMPTY = 0x7F7F7F7F;         // > any edge index; min-stable sentinel

// Two-stage select: 16 node chunks x 16 edge chunks, 1024-thread scan blocks.
constexpr int NC = 16;
constexpr int EC = 16;
constexpr int NODES_PER_NC = N_NODES / NC;      // 3125 (50 KB LDS table)
constexpr int EDGES_PER_EC = N_EDGES / EC;      // 50000
constexpr int E4_PER_EC    = EDGES_PER_EC / 4;  // 12500 int4 loads per chunk
constexpr int SEL_THREADS  = 1024;

constexpr int NBUCKETS = 16;              // stats buckets (cheap inline reduce)
constexpr int ZERO_WORDS = 2 * NBUCKETS * 256;   // 8192 = 8 stageA blocks x 1024

// x0 warm-stream: 1.6M float4s over 256 blocks x 1024 threads -> 7 each.
constexpr int X4_TOTAL = N_NODES * DIM4;         // 1,600,000
constexpr int WARM_ITERS = 7;                    // ceil(1.6M / 262144)

// Conv: proven structure. 256 threads = 8 nodes x 32 f4-cols, 2 iters.
// Layer 0 merges the 16 per-chunk top-4 lists inline and emits srcs4.
constexpr int NODES_PER_ITER  = 8;
constexpr int NODES_PER_BLOCK = 16;
constexpr int CONV_GRID = N_NODES / NODES_PER_BLOCK;   // 3125 exact, no guard

// BN apply: 5 tiles per block -> 1250 blocks.
constexpr int BN_TPB  = 5;
constexpr int BN_GRID = (N_NODES * DIM4 / 256) / BN_TPB;   // 1250 exact

// ---------------- helpers ----------------
__device__ inline float4 f4min(float4 a, float4 b) {
    return make_float4(fminf(a.x,b.x), fminf(a.y,b.y), fminf(a.z,b.z), fminf(a.w,b.w));
}
__device__ inline float4 f4max(float4 a, float4 b) {
    return make_float4(fmaxf(a.x,b.x), fmaxf(a.y,b.y), fmaxf(a.z,b.z), fmaxf(a.w,b.w));
}
__device__ inline float4 f4add(float4 a, float4 b) {
    return make_float4(a.x+b.x, a.y+b.y, a.z+b.z, a.w+b.w);
}
__device__ inline float4 f4fma(float s, float4 v, float4 acc) {   // acc + s*v
    return make_float4(fmaf(s,v.x,acc.x), fmaf(s,v.y,acc.y), fmaf(s,v.z,acc.z), fmaf(s,v.w,acc.w));
}
__device__ inline __half2 u2h2(unsigned u) { __half2 h; memcpy(&h, &u, 4); return h; }
__device__ inline unsigned h22u(__half2 h) { unsigned u; memcpy(&u, &h, 4); return u; }
__device__ inline float4 q2f4(uint2 q) {                 // fp16x4 -> fp32x4
    const float2 lo = __half22float2(u2h2(q.x));
    const float2 hi = __half22float2(u2h2(q.y));
    return make_float4(lo.x, lo.y, hi.x, hi.y);
}
__device__ inline uint2 f42q(float4 v) {                 // fp32x4 -> fp16x4
    uint2 u;
    u.x = h22u(__floats2half2_rn(v.x, v.y));
    u.y = h22u(__floats2half2_rn(v.z, v.w));
    return u;
}

// ---------------------------------------------------------------------------
// Select stage A: block (nc, ec) scans edge chunk ec with 1024 threads,
// inserts edges whose dst lies in node chunk nc into an LDS top-4 table
// (cascaded LDS atomicMin = concurrent sorted insert), then streams the
// table to tables[ec][node]. R12: additionally warm-streams x0 + src into
// the 256MB Infinity Cache while the scan's LDS atomics run — conv0's
// random gathers then hit L3 (~600cy) instead of cold HBM (~900cy).
// Housekeeping folded in: blocks 0-7 zero stats_part; blocks NC*EC /
// NC*EC+1 compute blank projections bp.
// ---------------------------------------------------------------------------
__global__ __launch_bounds__(SEL_THREADS)
void select_stageA_kernel(const int* __restrict__ dst,
                          const float* __restrict__ x0,
                          const int* __restrict__ src,
                          int* __restrict__ tables,
                          float* __restrict__ stats_part,
                          const float* __restrict__ W0, const float* __restrict__ b0,
                          const float* __restrict__ bl0,
                          const float* __restrict__ W1, const float* __restrict__ b1,
                          const float* __restrict__ bl1,
                          float* __restrict__ bp) {
    const int t = threadIdx.x;

    if (blockIdx.x >= NC * EC) {          // blank-projection blocks
        if (t < DIM) {
            int l = blockIdx.x - NC * EC;
            const float* W  = l ? W1  : W0;
            const float* b  = l ? b1  : b0;
            const float* bl = l ? bl1 : bl0;
            float s = 0.f;
            #pragma unroll 8
            for (int j = 0; j < DIM; ++j) s += W[t * DIM + j] * bl[j];
            bp[l * DIM + t] = s + b[t];
        }
        return;
    }

    const int gid = blockIdx.x * SEL_THREADS + t;
    if (gid < ZERO_WORDS) stats_part[gid] = 0.f;    // blocks 0-7 zero stats

    // ---- issue x0/src warm loads now; consume after the scan ----
    const float4* __restrict__ x04 = (const float4*)x0;
    float4 warm[WARM_ITERS];
    #pragma unroll
    for (int k = 0; k < WARM_ITERS; ++k) {
        int wi = gid + k * (NC * EC * SEL_THREADS);
        warm[k] = x04[wi < X4_TOTAL ? wi : 0];
    }
    int warm_s = (gid < N_EDGES / 4) ? ((const int4*)src)[gid].x : 0;

    __shared__ int slot[NODES_PER_NC * 4];    // 50 KB
    const int nc = blockIdx.x & (NC - 1);
    const int ec = blockIdx.x >> 4;

    int4* __restrict__ slot4 = (int4*)slot;
    for (int i = t; i < NODES_PER_NC; i += SEL_THREADS)
        slot4[i] = make_int4(EMPTY, EMPTY, EMPTY, EMPTY);
    __syncthreads();

    const int r0 = nc * NODES_PER_NC;
    const int4* __restrict__ dst4 = (const int4*)dst;
    const int base4 = ec * E4_PER_EC;
    for (int i = t; i < E4_PER_EC; i += SEL_THREADS) {
        const int4 d = dst4[base4 + i];
        // quick reject: all 4 dsts outside this node chunk (~77% of int4s)
        const int mn = min(min(d.x, d.y), min(d.z, d.w));
        const int mx = max(max(d.x, d.y), max(d.z, d.w));
        if (mx < r0 || mn >= r0 + NODES_PER_NC) continue;

        const int ebase = 4 * (base4 + i);
        #define TRY_INS(comp, off) {                                        \
            unsigned n_ = (unsigned)((comp) - r0);                          \
            if (n_ < (unsigned)NODES_PER_NC) {                              \
                int cur_ = ebase + (off);                                   \
                _Pragma("unroll")                                           \
                for (int j_ = 0; j_ < 4; ++j_) {                            \
                    int old_ = atomicMin(&slot[4 * n_ + j_], cur_);         \
                    if (old_ == EMPTY) break;                               \
                    cur_ = max(cur_, old_);                                 \
                } } }
        TRY_INS(d.x, 0); TRY_INS(d.y, 1); TRY_INS(d.z, 2); TRY_INS(d.w, 3);
        #undef TRY_INS
    }

    // consume warm loads (keep alive without side effects — rule #17)
    #pragma unroll
    for (int k = 0; k < WARM_ITERS; ++k) {
        asm volatile("" :: "v"(warm[k].x), "v"(warm[k].w));
    }
    asm volatile("" :: "v"(warm_s));

    __syncthreads();

    int4* __restrict__ out = (int4*)tables + (size_t)ec * N_NODES + r0;
    const int4* __restrict__ sl4 = (const int4*)slot;
    for (int n = t; n < NODES_PER_NC; n += SEL_THREADS) out[n] = sl4[n];
}

// ---------------------------------------------------------------------------
// Fused sort-conv + BN statistics. do_merge=1 (layer 0): cooperatively load
// the block's 16-node x 16-chunk table tile (4 KB, one coalesced shot),
// merge branchlessly (bitonic half-cleaner), map through src, publish srcs4
// for layer 1. do_merge=0 (layer 1): read srcs4. h stored fp16 (halved
// streaming traffic); BN statistics stay fp32 from registers.
// ---------------------------------------------------------------------------
__global__ __launch_bounds__(256)
void conv_stats_kernel(const float* __restrict__ x,
                       const int* __restrict__ tables,
                       const int* __restrict__ src,
                       int4* __restrict__ srcs4,
                       const float* __restrict__ bp,      // 128 floats (this layer)
                       const float* __restrict__ cw,
                       const float* __restrict__ cb,
                       const float* __restrict__ a,
                       uint2* __restrict__ h2,            // fp16 h out
                       float* __restrict__ stats_part,    // [NBUCKETS][256]
                       const int do_merge) {
    __shared__ int4 srcs_lds[NODES_PER_BLOCK];
    __shared__ int4 tile[EC][NODES_PER_BLOCK];

    const int t    = threadIdx.x;
    const int d4   = t & (DIM4 - 1);
    const int nsub = t >> 5;
    const int v0b  = blockIdx.x * NODES_PER_BLOCK;

    if (do_merge) {
        // one coalesced tile load: thread t -> chunk t>>4, node t&15
        tile[t >> 4][t & 15] =
            ((const int4*)tables)[(size_t)(t >> 4) * N_NODES + v0b + (t & 15)];
        __syncthreads();
        if (t < NODES_PER_BLOCK) {
            int4 c = tile[0][t];
            int a0 = c.x, a1 = c.y, a2 = c.z, a3 = c.w;
            #define MERGE4(cx, cy, cz, cw_) {                            \
                int m0 = min(a0, (cw_)), m1 = min(a1, (cz));             \
                int m2 = min(a2, (cy)), m3 = min(a3, (cx));              \
                int u_;                                                  \
                u_ = min(m0, m2); m2 = max(m0, m2); m0 = u_;             \
                u_ = min(m1, m3); m3 = max(m1, m3); m1 = u_;             \
                u_ = min(m0, m1); m1 = max(m0, m1); m0 = u_;             \
                u_ = min(m2, m3); m3 = max(m2, m3); m2 = u_;             \
                a0 = m0; a1 = m1; a2 = m2; a3 = m3; }
            #pragma unroll
            for (int ec = 1; ec < EC; ++ec) {
                c = tile[ec][t];
                MERGE4(c.x, c.y, c.z, c.w);
            }
            #undef MERGE4
            int4 r;
            r.x = (a0 < N_EDGES) ? src[a0] : -1;
            r.y = (a1 < N_EDGES) ? src[a1] : -1;
            r.z = (a2 < N_EDGES) ? src[a2] : -1;
            r.w = (a3 < N_EDGES) ? src[a3] : -1;
            srcs_lds[t] = r;
            srcs4[v0b + t] = r;               // publish for layer 1
        }
        __syncthreads();
    } else {
        if (t < NODES_PER_BLOCK) srcs_lds[t] = srcs4[v0b + t];
        __syncthreads();
    }

    const float4* __restrict__ x4 = (const float4*)x;

    const float aa = a[0];
    const float c0 = cw[0], c1 = cw[1], c2 = cw[2], c3 = cw[3];
    const float cbv = cb[0];
    const float4 bpv = ((const float4*)bp)[d4];

    const int v0 = v0b + nsub;
    const int v1 = v0 + NODES_PER_ITER;

    const int4 s0 = srcs_lds[nsub];
    const int4 s1 = srcs_lds[nsub + NODES_PER_ITER];

    // unconditional gathers (clamped row), selects afterwards
    float4 g00 = x4[(size_t)max(s0.x, 0) * DIM4 + d4];
    float4 g01 = x4[(size_t)max(s0.y, 0) * DIM4 + d4];
    float4 g02 = x4[(size_t)max(s0.z, 0) * DIM4 + d4];
    float4 g03 = x4[(size_t)max(s0.w, 0) * DIM4 + d4];
    float4 g10 = x4[(size_t)max(s1.x, 0) * DIM4 + d4];
    float4 g11 = x4[(size_t)max(s1.y, 0) * DIM4 + d4];
    float4 g12 = x4[(size_t)max(s1.z, 0) * DIM4 + d4];
    float4 g13 = x4[(size_t)max(s1.w, 0) * DIM4 + d4];
    float4 xv0 = x4[(size_t)v0 * DIM4 + d4];
    float4 xv1 = x4[(size_t)v1 * DIM4 + d4];

    float4 s  = make_float4(0.f, 0.f, 0.f, 0.f);
    float4 s2 = make_float4(0.f, 0.f, 0.f, 0.f);

    #define CSWAP4(p, q) { float4 lo = f4min(p, q); float4 hi = f4max(p, q); p = lo; q = hi; }
    {
        float4 m0 = (s0.x >= 0) ? g00 : bpv;
        float4 m1 = (s0.y >= 0) ? g01 : bpv;
        float4 m2 = (s0.z >= 0) ? g02 : bpv;
        float4 m3 = (s0.w >= 0) ? g03 : bpv;
        CSWAP4(m0, m1); CSWAP4(m2, m3); CSWAP4(m0, m2); CSWAP4(m1, m3); CSWAP4(m1, m2);
        float4 hv = make_float4(cbv, cbv, cbv, cbv);
        hv = f4fma(c0, m0, hv);
        hv = f4fma(c1, m1, hv);
        hv = f4fma(c2, m2, hv);
        hv = f4fma(c3, m3, hv);
        hv = f4fma(aa, xv0, hv);
        h2[(size_t)v0 * DIM4 + d4] = f42q(hv);
        s  = f4add(s, hv);
        s2 = f4add(s2, make_float4(hv.x*hv.x, hv.y*hv.y, hv.z*hv.z, hv.w*hv.w));
    }
    {
        float4 m0 = (s1.x >= 0) ? g10 : bpv;
        float4 m1 = (s1.y >= 0) ? g11 : bpv;
        float4 m2 = (s1.z >= 0) ? g12 : bpv;
        float4 m3 = (s1.w >= 0) ? g13 : bpv;
        CSWAP4(m0, m1); CSWAP4(m2, m3); CSWAP4(m0, m2); CSWAP4(m1, m3); CSWAP4(m1, m2);
        float4 hv = make_float4(cbv, cbv, cbv, cbv);
        hv = f4fma(c0, m0, hv);
        hv = f4fma(c1, m1, hv);
        hv = f4fma(c2, m2, hv);
        hv = f4fma(c3, m3, hv);
        hv = f4fma(aa, xv1, hv);
        h2[(size_t)v1 * DIM4 + d4] = f42q(hv);
        s  = f4add(s, hv);
        s2 = f4add(s2, make_float4(hv.x*hv.x, hv.y*hv.y, hv.z*hv.z, hv.w*hv.w));
    }
    #undef CSWAP4

    // intra-wave: lane i += lane i+32 (same d4 column, different node)
    s.x  += __shfl_down(s.x, 32);  s.y  += __shfl_down(s.y, 32);
    s.z  += __shfl_down(s.z, 32);  s.w  += __shfl_down(s.w, 32);
    s2.x += __shfl_down(s2.x, 32); s2.y += __shfl_down(s2.y, 32);
    s2.z += __shfl_down(s2.z, 32); s2.w += __shfl_down(s2.w, 32);

    __shared__ float4 ls[4][32];
    __shared__ float4 ls2[4][32];
    const int wave = t >> 6;
    const int lane = t & 63;
    if (lane < 32) { ls[wave][lane] = s; ls2[wave][lane] = s2; }
    __syncthreads();
    if (t < 32) {
        float* bucket = stats_part + (size_t)(blockIdx.x & (NBUCKETS - 1)) * 256;
        float4 fs  = f4add(f4add(ls[0][t],  ls[1][t]),  f4add(ls[2][t],  ls[3][t]));
        float4 fs2 = f4add(f4add(ls2[0][t], ls2[1][t]), f4add(ls2[2][t], ls2[3][t]));
        atomicAdd(&bucket[4*t + 0], fs.x);
        atomicAdd(&bucket[4*t + 1], fs.y);
        atomicAdd(&bucket[4*t + 2], fs.z);
        atomicAdd(&bucket[4*t + 3], fs.w);
        atomicAdd(&bucket[DIM + 4*t + 0], fs2.x);
        atomicAdd(&bucket[DIM + 4*t + 1], fs2.y);
        atomicAdd(&bucket[DIM + 4*t + 2], fs2.z);
        atomicAdd(&bucket[DIM + 4*t + 3], fs2.w);
    }
}

// ---------------------------------------------------------------------------
// BN apply with inline bucket finalize: each block sums the 16 bucket
// partials ONCE, then applies BN+residual to 5 tiles. h read as fp16.
// ---------------------------------------------------------------------------
__global__ __launch_bounds__(256)
void bn_apply_kernel(const float* __restrict__ xin,
                     const uint2* __restrict__ h2,
                     const float* __restrict__ stats_part,  // [NBUCKETS][256]
                     const float* __restrict__ g,
                     const float* __restrict__ be,
                     float* __restrict__ xout) {
    __shared__ float acc[256];
    const int t = threadIdx.x;

    float ssum = 0.f;
    #pragma unroll
    for (int k = 0; k < NBUCKETS; ++k) ssum += stats_part[k * 256 + t];
    acc[t] = ssum;
    __syncthreads();
    if (t < 128) {
        constexpr float invN = 1.0f / (float)N_NODES;
        float mu = acc[t] * invN;
        float iv = rsqrtf(acc[128 + t] * invN - mu * mu + BN_EPS);
        acc[t]       = mu;
        acc[128 + t] = iv;
    }
    __syncthreads();

    const int d4 = t & (DIM4 - 1);
    const float4 mu4 = make_float4(acc[4*d4+0], acc[4*d4+1], acc[4*d4+2], acc[4*d4+3]);
    const float4 iv4 = make_float4(acc[128+4*d4+0], acc[128+4*d4+1],
                                   acc[128+4*d4+2], acc[128+4*d4+3]);
    const float4 gv = ((const float4*)g)[d4];
    const float4 bv = ((const float4*)be)[d4];

    #pragma unroll
    for (int k = 0; k < BN_TPB; ++k) {
        const int idx = (blockIdx.x * BN_TPB + k) * 256 + t;   // float4 idx; exact
        const float4 hv = q2f4(h2[idx]);
        const float4 xv = ((const float4*)xin)[idx];
        float4 o;
        o.x = xv.x + (hv.x - mu4.x) * iv4.x * gv.x + bv.x;
        o.y = xv.y + (hv.y - mu4.y) * iv4.y * gv.y + bv.y;
        o.z = xv.z + (hv.z - mu4.z) * iv4.z * gv.z + bv.z;
        o.w = xv.w + (hv.w - mu4.w) * iv4.w * gv.w + bv.w;
        ((float4*)xout)[idx] = o;
    }
}

extern "C" void kernel_launch(void* const* d_in, const int* in_sizes, int n_in,
                              void* d_out, int out_size, void* d_ws, size_t ws_size,
                              hipStream_t stream) {
    const float* x0  = (const float*)d_in[0];
    const int*   ei  = (const int*)d_in[1];
    const int*   src = ei;               // edge_index[0]
    const int*   dst = ei + N_EDGES;     // edge_index[1]

    const float* W[2]; const float* b[2]; const float* cw[2]; const float* cb[2];
    const float* a[2]; const float* g[2]; const float* be[2]; const float* blank[2];
    for (int i = 0; i < 2; ++i) {
        int o = 2 + 8 * i;
        W[i]     = (const float*)d_in[o + 0];
        b[i]     = (const float*)d_in[o + 1];
        cw[i]    = (const float*)d_in[o + 2];
        cb[i]    = (const float*)d_in[o + 3];
        a[i]     = (const float*)d_in[o + 4];
        g[i]     = (const float*)d_in[o + 5];
        be[i]    = (const float*)d_in[o + 6];
        blank[i] = (const float*)d_in[o + 7];
    }

    // Workspace layout (re-poisoned 0xAA each call — everything used is
    // written before read). No aliasing: conv0 reads tables while writing
    // h2 and srcs4.
    char* ws = (char*)d_ws;
    int*   srcs       = (int*)ws;                                 // 4N ints = 0.8 MB
    int*   tables     = srcs + 4 * N_NODES;                       // 16*4N ints = 12.8 MB
    uint2* h2         = (uint2*)(tables + (size_t)EC * 4 * N_NODES); // 12.8 MB fp16 h
    float* stats_part = (float*)(h2 + (size_t)N_NODES * DIM4);    // 2*16*256 floats
    float* bp         = stats_part + ZERO_WORDS;                  // 256 floats

    float* xout = (float*)d_out;

    // ---- selection stage A (+ L3 warm of x0/src + stats zero + bp) ----
    select_stageA_kernel<<<NC * EC + 2, SEL_THREADS, 0, stream>>>(
        dst, x0, src, tables, stats_part,
        W[0], b[0], blank[0], W[1], b[1], blank[1], bp);

    // ---- two layers: conv+stats (l0 merges inline), BN apply ----
    for (int l = 0; l < 2; ++l) {
        const float* xin = (l == 0) ? x0 : xout;
        float* sp = stats_part + (size_t)l * NBUCKETS * 256;
        conv_stats_kernel<<<CONV_GRID, 256, 0, stream>>>(
            xin, tables, src, (int4*)srcs, bp + l * DIM,
            cw[l], cb[l], a[l], h2, sp, (l == 0) ? 1 : 0);
        bn_apply_kernel<<<BN_GRID, 256, 0, stream>>>(
            xin, h2, sp, g[l], be[l], xout);
    }
}

// Round 13
// 196.427 us; speedup vs baseline: 1.0285x; 1.0285x over previous
//
#include <hip/hip_runtime.h>
#include <hip/hip_fp16.h>
#include <cstring>

// Problem constants (fixed by reference setup_inputs)
constexpr int N_NODES = 50000;
constexpr int N_EDGES = 800000;
constexpr int DIM     = 128;
constexpr int DIM4    = DIM / 4;          // 32 float4 columns
constexpr float BN_EPS = 1e-5f;

constexpr int EMPTY = 0x7F7F7F7F;         // > any edge index; min-stable sentinel

// Two-stage select: 16 node chunks x 16 edge chunks, 1024-thread scan blocks.
constexpr int NC = 16;
constexpr int EC = 16;
constexpr int NODES_PER_NC = N_NODES / NC;      // 3125 (50 KB LDS table)
constexpr int EDGES_PER_EC = N_EDGES / EC;      // 50000
constexpr int E4_PER_EC    = EDGES_PER_EC / 4;  // 12500 int4 loads per chunk
constexpr int SEL_THREADS  = 1024;

constexpr int NBUCKETS = 16;              // stats buckets (cheap inline reduce)
constexpr int ZERO_WORDS = 2 * NBUCKETS * 256;   // 8192 = 8 stageA blocks x 1024

// Conv: proven R4 structure. 256 threads = 8 nodes x 32 f4-cols, 2 iters.
// Layer 0 additionally merges the 16 per-chunk top-4 lists inline (stageB
// eliminated) and emits srcs4 for layer 1.
constexpr int NODES_PER_ITER  = 8;
constexpr int NODES_PER_BLOCK = 16;
constexpr int CONV_GRID = N_NODES / NODES_PER_BLOCK;   // 3125 exact, no guard

// BN apply: 5 tiles per block -> 1250 blocks; amortizes the per-block
// bucket reduction 5x.
constexpr int BN_TPB  = 5;
constexpr int BN_GRID = (N_NODES * DIM4 / 256) / BN_TPB;   // 1250 exact

// ---------------- helpers ----------------
__device__ inline float4 f4min(float4 a, float4 b) {
    return make_float4(fminf(a.x,b.x), fminf(a.y,b.y), fminf(a.z,b.z), fminf(a.w,b.w));
}
__device__ inline float4 f4max(float4 a, float4 b) {
    return make_float4(fmaxf(a.x,b.x), fmaxf(a.y,b.y), fmaxf(a.z,b.z), fmaxf(a.w,b.w));
}
__device__ inline float4 f4add(float4 a, float4 b) {
    return make_float4(a.x+b.x, a.y+b.y, a.z+b.z, a.w+b.w);
}
__device__ inline float4 f4fma(float s, float4 v, float4 acc) {   // acc + s*v
    return make_float4(fmaf(s,v.x,acc.x), fmaf(s,v.y,acc.y), fmaf(s,v.z,acc.z), fmaf(s,v.w,acc.w));
}
__device__ inline __half2 u2h2(unsigned u) { __half2 h; memcpy(&h, &u, 4); return h; }
__device__ inline unsigned h22u(__half2 h) { unsigned u; memcpy(&u, &h, 4); return u; }
__device__ inline float4 q2f4(uint2 q) {                 // fp16x4 -> fp32x4
    const float2 lo = __half22float2(u2h2(q.x));
    const float2 hi = __half22float2(u2h2(q.y));
    return make_float4(lo.x, lo.y, hi.x, hi.y);
}
__device__ inline uint2 f42q(float4 v) {                 // fp32x4 -> fp16x4
    uint2 u;
    u.x = h22u(__floats2half2_rn(v.x, v.y));
    u.y = h22u(__floats2half2_rn(v.z, v.w));
    return u;
}

// ---------------------------------------------------------------------------
// Select stage A: block (nc, ec) scans edge chunk ec with 1024 threads,
// inserts edges whose dst lies in node chunk nc into an LDS top-4 table
// (cascaded LDS atomicMin = concurrent sorted insert), then streams the
// table to tables[ec][node]. Housekeeping folded in: blocks 0-7 zero
// stats_part; blocks NC*EC / NC*EC+1 compute blank projections bp.
// ---------------------------------------------------------------------------
__global__ __launch_bounds__(SEL_THREADS)
void select_stageA_kernel(const int* __restrict__ dst,
                          int* __restrict__ tables,
                          float* __restrict__ stats_part,
                          const float* __restrict__ W0, const float* __restrict__ b0,
                          const float* __restrict__ bl0,
                          const float* __restrict__ W1, const float* __restrict__ b1,
                          const float* __restrict__ bl1,
                          float* __restrict__ bp) {
    const int t = threadIdx.x;

    if (blockIdx.x >= NC * EC) {          // blank-projection blocks
        if (t < DIM) {
            int l = blockIdx.x - NC * EC;
            const float* W  = l ? W1  : W0;
            const float* b  = l ? b1  : b0;
            const float* bl = l ? bl1 : bl0;
            float s = 0.f;
            #pragma unroll 8
            for (int j = 0; j < DIM; ++j) s += W[t * DIM + j] * bl[j];
            bp[l * DIM + t] = s + b[t];
        }
        return;
    }

    const int gid = blockIdx.x * SEL_THREADS + t;
    if (gid < ZERO_WORDS) stats_part[gid] = 0.f;    // blocks 0-7 zero stats

    __shared__ int slot[NODES_PER_NC * 4];    // 50 KB
    const int nc = blockIdx.x & (NC - 1);
    const int ec = blockIdx.x >> 4;

    for (int i = t; i < NODES_PER_NC * 4; i += SEL_THREADS) slot[i] = EMPTY;
    __syncthreads();

    const int r0 = nc * NODES_PER_NC;
    const int4* __restrict__ dst4 = (const int4*)dst;
    const int base4 = ec * E4_PER_EC;
    for (int i = t; i < E4_PER_EC; i += SEL_THREADS) {
        const int4 d = dst4[base4 + i];
        const int ebase = 4 * (base4 + i);
        #define TRY_INS(comp, off) {                                        \
            unsigned n_ = (unsigned)((comp) - r0);                          \
            if (n_ < (unsigned)NODES_PER_NC) {                              \
                int cur_ = ebase + (off);                                   \
                _Pragma("unroll")                                           \
                for (int j_ = 0; j_ < 4; ++j_) {                            \
                    int old_ = atomicMin(&slot[4 * n_ + j_], cur_);         \
                    if (old_ == EMPTY) break;                               \
                    cur_ = max(cur_, old_);                                 \
                } } }
        TRY_INS(d.x, 0); TRY_INS(d.y, 1); TRY_INS(d.z, 2); TRY_INS(d.w, 3);
        #undef TRY_INS
    }
    __syncthreads();

    int4* __restrict__ out = (int4*)tables + (size_t)ec * N_NODES + r0;
    const int4* __restrict__ sl4 = (const int4*)slot;
    for (int n = t; n < NODES_PER_NC; n += SEL_THREADS) out[n] = sl4[n];
}

// ---------------------------------------------------------------------------
// Fused sort-conv + BN statistics. do_merge=1 (layer 0): cooperatively load
// the block's 16-node x 16-chunk table tile (4 KB, one coalesced shot),
// merge branchlessly (bitonic half-cleaner), map through src, publish srcs4
// for layer 1 — stageB kernel eliminated. do_merge=0 (layer 1): read srcs4.
// h is stored fp16 (uint2/node-col): halves the h streaming traffic; BN
// statistics stay fp32 from registers.
// ---------------------------------------------------------------------------
__global__ __launch_bounds__(256)
void conv_stats_kernel(const float* __restrict__ x,
                       const int* __restrict__ tables,
                       const int* __restrict__ src,
                       int4* __restrict__ srcs4,
                       const float* __restrict__ bp,      // 128 floats (this layer)
                       const float* __restrict__ cw,
                       const float* __restrict__ cb,
                       const float* __restrict__ a,
                       uint2* __restrict__ h2,            // fp16 h out
                       float* __restrict__ stats_part,    // [NBUCKETS][256]
                       const int do_merge) {
    __shared__ int4 srcs_lds[NODES_PER_BLOCK];
    __shared__ int4 tile[EC][NODES_PER_BLOCK];

    const int t    = threadIdx.x;
    const int d4   = t & (DIM4 - 1);
    const int nsub = t >> 5;
    const int v0b  = blockIdx.x * NODES_PER_BLOCK;

    if (do_merge) {
        // one coalesced tile load: thread t -> chunk t>>4, node t&15
        tile[t >> 4][t & 15] =
            ((const int4*)tables)[(size_t)(t >> 4) * N_NODES + v0b + (t & 15)];
        __syncthreads();
        if (t < NODES_PER_BLOCK) {
            int4 c = tile[0][t];
            int a0 = c.x, a1 = c.y, a2 = c.z, a3 = c.w;
            #define MERGE4(cx, cy, cz, cw_) {                            \
                int m0 = min(a0, (cw_)), m1 = min(a1, (cz));             \
                int m2 = min(a2, (cy)), m3 = min(a3, (cx));              \
                int u_;                                                  \
                u_ = min(m0, m2); m2 = max(m0, m2); m0 = u_;             \
                u_ = min(m1, m3); m3 = max(m1, m3); m1 = u_;             \
                u_ = min(m0, m1); m1 = max(m0, m1); m0 = u_;             \
                u_ = min(m2, m3); m3 = max(m2, m3); m2 = u_;             \
                a0 = m0; a1 = m1; a2 = m2; a3 = m3; }
            #pragma unroll
            for (int ec = 1; ec < EC; ++ec) {
                c = tile[ec][t];
                MERGE4(c.x, c.y, c.z, c.w);
            }
            #undef MERGE4
            int4 r;
            r.x = (a0 < N_EDGES) ? src[a0] : -1;
            r.y = (a1 < N_EDGES) ? src[a1] : -1;
            r.z = (a2 < N_EDGES) ? src[a2] : -1;
            r.w = (a3 < N_EDGES) ? src[a3] : -1;
            srcs_lds[t] = r;
            srcs4[v0b + t] = r;               // publish for layer 1
        }
        __syncthreads();
    } else {
        if (t < NODES_PER_BLOCK) srcs_lds[t] = srcs4[v0b + t];
        __syncthreads();
    }

    const float4* __restrict__ x4 = (const float4*)x;

    const float aa = a[0];
    const float c0 = cw[0], c1 = cw[1], c2 = cw[2], c3 = cw[3];
    const float cbv = cb[0];
    const float4 bpv = ((const float4*)bp)[d4];

    const int v0 = v0b + nsub;
    const int v1 = v0 + NODES_PER_ITER;

    const int4 s0 = srcs_lds[nsub];
    const int4 s1 = srcs_lds[nsub + NODES_PER_ITER];

    // unconditional gathers (clamped row), selects afterwards
    float4 g00 = x4[(size_t)max(s0.x, 0) * DIM4 + d4];
    float4 g01 = x4[(size_t)max(s0.y, 0) * DIM4 + d4];
    float4 g02 = x4[(size_t)max(s0.z, 0) * DIM4 + d4];
    float4 g03 = x4[(size_t)max(s0.w, 0) * DIM4 + d4];
    float4 g10 = x4[(size_t)max(s1.x, 0) * DIM4 + d4];
    float4 g11 = x4[(size_t)max(s1.y, 0) * DIM4 + d4];
    float4 g12 = x4[(size_t)max(s1.z, 0) * DIM4 + d4];
    float4 g13 = x4[(size_t)max(s1.w, 0) * DIM4 + d4];
    float4 xv0 = x4[(size_t)v0 * DIM4 + d4];
    float4 xv1 = x4[(size_t)v1 * DIM4 + d4];

    float4 s  = make_float4(0.f, 0.f, 0.f, 0.f);
    float4 s2 = make_float4(0.f, 0.f, 0.f, 0.f);

    #define CSWAP4(p, q) { float4 lo = f4min(p, q); float4 hi = f4max(p, q); p = lo; q = hi; }
    {
        float4 m0 = (s0.x >= 0) ? g00 : bpv;
        float4 m1 = (s0.y >= 0) ? g01 : bpv;
        float4 m2 = (s0.z >= 0) ? g02 : bpv;
        float4 m3 = (s0.w >= 0) ? g03 : bpv;
        CSWAP4(m0, m1); CSWAP4(m2, m3); CSWAP4(m0, m2); CSWAP4(m1, m3); CSWAP4(m1, m2);
        float4 hv = make_float4(cbv, cbv, cbv, cbv);
        hv = f4fma(c0, m0, hv);
        hv = f4fma(c1, m1, hv);
        hv = f4fma(c2, m2, hv);
        hv = f4fma(c3, m3, hv);
        hv = f4fma(aa, xv0, hv);
        h2[(size_t)v0 * DIM4 + d4] = f42q(hv);
        s  = f4add(s, hv);
        s2 = f4add(s2, make_float4(hv.x*hv.x, hv.y*hv.y, hv.z*hv.z, hv.w*hv.w));
    }
    {
        float4 m0 = (s1.x >= 0) ? g10 : bpv;
        float4 m1 = (s1.y >= 0) ? g11 : bpv;
        float4 m2 = (s1.z >= 0) ? g12 : bpv;
        float4 m3 = (s1.w >= 0) ? g13 : bpv;
        CSWAP4(m0, m1); CSWAP4(m2, m3); CSWAP4(m0, m2); CSWAP4(m1, m3); CSWAP4(m1, m2);
        float4 hv = make_float4(cbv, cbv, cbv, cbv);
        hv = f4fma(c0, m0, hv);
        hv = f4fma(c1, m1, hv);
        hv = f4fma(c2, m2, hv);
        hv = f4fma(c3, m3, hv);
        hv = f4fma(aa, xv1, hv);
        h2[(size_t)v1 * DIM4 + d4] = f42q(hv);
        s  = f4add(s, hv);
        s2 = f4add(s2, make_float4(hv.x*hv.x, hv.y*hv.y, hv.z*hv.z, hv.w*hv.w));
    }
    #undef CSWAP4

    // intra-wave: lane i += lane i+32 (same d4 column, different node)
    s.x  += __shfl_down(s.x, 32);  s.y  += __shfl_down(s.y, 32);
    s.z  += __shfl_down(s.z, 32);  s.w  += __shfl_down(s.w, 32);
    s2.x += __shfl_down(s2.x, 32); s2.y += __shfl_down(s2.y, 32);
    s2.z += __shfl_down(s2.z, 32); s2.w += __shfl_down(s2.w, 32);

    __shared__ float4 ls[4][32];
    __shared__ float4 ls2[4][32];
    const int wave = t >> 6;
    const int lane = t & 63;
    if (lane < 32) { ls[wave][lane] = s; ls2[wave][lane] = s2; }
    __syncthreads();
    if (t < 32) {
        float* bucket = stats_part + (size_t)(blockIdx.x & (NBUCKETS - 1)) * 256;
        float4 fs  = f4add(f4add(ls[0][t],  ls[1][t]),  f4add(ls[2][t],  ls[3][t]));
        float4 fs2 = f4add(f4add(ls2[0][t], ls2[1][t]), f4add(ls2[2][t], ls2[3][t]));
        atomicAdd(&bucket[4*t + 0], fs.x);
        atomicAdd(&bucket[4*t + 1], fs.y);
        atomicAdd(&bucket[4*t + 2], fs.z);
        atomicAdd(&bucket[4*t + 3], fs.w);
        atomicAdd(&bucket[DIM + 4*t + 0], fs2.x);
        atomicAdd(&bucket[DIM + 4*t + 1], fs2.y);
        atomicAdd(&bucket[DIM + 4*t + 2], fs2.z);
        atomicAdd(&bucket[DIM + 4*t + 3], fs2.w);
    }
}

// ---------------------------------------------------------------------------
// BN apply with inline bucket finalize: each block sums the 16 bucket
// partials ONCE, then applies BN+residual to 5 tiles (grid-stride) — the
// reduction redundancy is amortized 5x vs one-tile blocks. h read as fp16.
// ---------------------------------------------------------------------------
__global__ __launch_bounds__(256)
void bn_apply_kernel(const float* __restrict__ xin,
                     const uint2* __restrict__ h2,
                     const float* __restrict__ stats_part,  // [NBUCKETS][256]
                     const float* __restrict__ g,
                     const float* __restrict__ be,
                     float* __restrict__ xout) {
    __shared__ float acc[256];
    const int t = threadIdx.x;

    float ssum = 0.f;
    #pragma unroll
    for (int k = 0; k < NBUCKETS; ++k) ssum += stats_part[k * 256 + t];
    acc[t] = ssum;
    __syncthreads();
    if (t < 128) {
        constexpr float invN = 1.0f / (float)N_NODES;
        float mu = acc[t] * invN;
        float iv = rsqrtf(acc[128 + t] * invN - mu * mu + BN_EPS);
        acc[t]       = mu;
        acc[128 + t] = iv;
    }
    __syncthreads();

    const int d4 = t & (DIM4 - 1);
    const float4 mu4 = make_float4(acc[4*d4+0], acc[4*d4+1], acc[4*d4+2], acc[4*d4+3]);
    const float4 iv4 = make_float4(acc[128+4*d4+0], acc[128+4*d4+1],
                                   acc[128+4*d4+2], acc[128+4*d4+3]);
    const float4 gv = ((const float4*)g)[d4];
    const float4 bv = ((const float4*)be)[d4];

    #pragma unroll
    for (int k = 0; k < BN_TPB; ++k) {
        const int idx = (blockIdx.x * BN_TPB + k) * 256 + t;   // float4 idx; exact
        const float4 hv = q2f4(h2[idx]);
        const float4 xv = ((const float4*)xin)[idx];
        float4 o;
        o.x = xv.x + (hv.x - mu4.x) * iv4.x * gv.x + bv.x;
        o.y = xv.y + (hv.y - mu4.y) * iv4.y * gv.y + bv.y;
        o.z = xv.z + (hv.z - mu4.z) * iv4.z * gv.z + bv.z;
        o.w = xv.w + (hv.w - mu4.w) * iv4.w * gv.w + bv.w;
        ((float4*)xout)[idx] = o;
    }
}

extern "C" void kernel_launch(void* const* d_in, const int* in_sizes, int n_in,
                              void* d_out, int out_size, void* d_ws, size_t ws_size,
                              hipStream_t stream) {
    const float* x0  = (const float*)d_in[0];
    const int*   ei  = (const int*)d_in[1];
    const int*   src = ei;               // edge_index[0]
    const int*   dst = ei + N_EDGES;     // edge_index[1]

    const float* W[2]; const float* b[2]; const float* cw[2]; const float* cb[2];
    const float* a[2]; const float* g[2]; const float* be[2]; const float* blank[2];
    for (int i = 0; i < 2; ++i) {
        int o = 2 + 8 * i;
        W[i]     = (const float*)d_in[o + 0];
        b[i]     = (const float*)d_in[o + 1];
        cw[i]    = (const float*)d_in[o + 2];
        cb[i]    = (const float*)d_in[o + 3];
        a[i]     = (const float*)d_in[o + 4];
        g[i]     = (const float*)d_in[o + 5];
        be[i]    = (const float*)d_in[o + 6];
        blank[i] = (const float*)d_in[o + 7];
    }

    // Workspace layout (re-poisoned 0xAA each call — everything used is
    // written before read). No aliasing: conv0 reads tables while writing
    // h2 and srcs4.
    char* ws = (char*)d_ws;
    int*   srcs       = (int*)ws;                                 // 4N ints = 0.8 MB
    int*   tables     = srcs + 4 * N_NODES;                       // 16*4N ints = 12.8 MB
    uint2* h2         = (uint2*)(tables + (size_t)EC * 4 * N_NODES); // 12.8 MB fp16 h
    float* stats_part = (float*)(h2 + (size_t)N_NODES * DIM4);    // 2*16*256 floats
    float* bp         = stats_part + ZERO_WORDS;                  // 256 floats

    float* xout = (float*)d_out;

    // ---- selection stage A (+ stats zero + blank projections) ----
    select_stageA_kernel<<<NC * EC + 2, SEL_THREADS, 0, stream>>>(
        dst, tables, stats_part,
        W[0], b[0], blank[0], W[1], b[1], blank[1], bp);

    // ---- two layers: conv+stats (l0 merges inline), BN apply ----
    for (int l = 0; l < 2; ++l) {
        const float* xin = (l == 0) ? x0 : xout;
        float* sp = stats_part + (size_t)l * NBUCKETS * 256;
        conv_stats_kernel<<<CONV_GRID, 256, 0, stream>>>(
            xin, tables, src, (int4*)srcs, bp + l * DIM,
            cw[l], cb[l], a[l], h2, sp, (l == 0) ? 1 : 0);
        bn_apply_kernel<<<BN_GRID, 256, 0, stream>>>(
            xin, h2, sp, g[l], be[l], xout);
    }
}